// Round 1
// baseline (1735.598 us; speedup 1.0000x reference)
//
#include <hip/hip_runtime.h>
#include <hip/hip_bf16.h>

#define D_DIM 512
#define K_CL  128
#define TEMP  30.0f

// ---------------- K1: z = x @ W  (M x 512)(512 x 512), fp32 tiled ----------
// BM=128 BN=128 BK=32, 256 threads, 8x8 register tile per thread.
__launch_bounds__(256)
__global__ void k_gemm(const float* __restrict__ x, const float* __restrict__ w,
                       float* __restrict__ z, int M) {
  __shared__ float As[32][132];   // [k][m], padded stride 132
  __shared__ float Bs[32][132];   // [k][n]
  const int t  = threadIdx.x;
  const int tx = t & 15, ty = t >> 4;
  const int m0 = blockIdx.x * 128;
  const int n0 = blockIdx.y * 128;
  float acc[8][8] = {};
  for (int k0 = 0; k0 < D_DIM; k0 += 32) {
    // stage A tile 128x32 (transposed into LDS)
#pragma unroll
    for (int i = 0; i < 4; ++i) {
      int c = t + i * 256;
      int r = c >> 3, kc = (c & 7) << 2;
      float4 v = make_float4(0.f, 0.f, 0.f, 0.f);
      if (m0 + r < M)
        v = *(const float4*)(x + (size_t)(m0 + r) * D_DIM + k0 + kc);
      As[kc + 0][r] = v.x; As[kc + 1][r] = v.y;
      As[kc + 2][r] = v.z; As[kc + 3][r] = v.w;
    }
    // stage B tile 32x128
#pragma unroll
    for (int i = 0; i < 4; ++i) {
      int c = t + i * 256;
      int kr = c >> 5, nc = (c & 31) << 2;
      *(float4*)&Bs[kr][nc] =
          *(const float4*)(w + (size_t)(k0 + kr) * D_DIM + n0 + nc);
    }
    __syncthreads();
#pragma unroll
    for (int kk = 0; kk < 32; ++kk) {
      float4 a0 = *(const float4*)&As[kk][ty * 8];
      float4 a1 = *(const float4*)&As[kk][ty * 8 + 4];
      float4 b0 = *(const float4*)&Bs[kk][tx * 8];
      float4 b1 = *(const float4*)&Bs[kk][tx * 8 + 4];
      float a[8] = {a0.x, a0.y, a0.z, a0.w, a1.x, a1.y, a1.z, a1.w};
      float b[8] = {b0.x, b0.y, b0.z, b0.w, b1.x, b1.y, b1.z, b1.w};
#pragma unroll
      for (int i = 0; i < 8; ++i)
#pragma unroll
        for (int j = 0; j < 8; ++j)
          acc[i][j] = fmaf(a[i], b[j], acc[i][j]);
    }
    __syncthreads();
  }
#pragma unroll
  for (int i = 0; i < 8; ++i) {
    int m = m0 + ty * 8 + i;
    if (m < M) {
      float* p = z + (size_t)m * D_DIM + n0 + tx * 8;
      *(float4*)p       = make_float4(acc[i][0], acc[i][1], acc[i][2], acc[i][3]);
      *(float4*)(p + 4) = make_float4(acc[i][4], acc[i][5], acc[i][6], acc[i][7]);
    }
  }
}

// ---------------- K2: row L2-normalize in place (one wave per row) ---------
__launch_bounds__(256)
__global__ void k_norm(float* __restrict__ z, int M) {
  const int gw   = (blockIdx.x * 256 + threadIdx.x) >> 6;
  const int lane = threadIdx.x & 63;
  if (gw >= M) return;                       // wave-uniform
  float4* row = (float4*)(z + (size_t)gw * D_DIM);
  float4 a = row[lane * 2], b = row[lane * 2 + 1];
  float ss = a.x * a.x + a.y * a.y + a.z * a.z + a.w * a.w +
             b.x * b.x + b.y * b.y + b.z * b.z + b.w * b.w;
#pragma unroll
  for (int m = 1; m < 64; m <<= 1) ss += __shfl_xor(ss, m);
  const float s = 1.0f / sqrtf(ss);
  a.x *= s; a.y *= s; a.z *= s; a.w *= s;
  b.x *= s; b.y *= s; b.z *= s; b.w *= s;
  row[lane * 2] = a; row[lane * 2 + 1] = b;
}

// ---------------- K3: histogram of comm_labels -> counts (float) -----------
__global__ void k_count(const int* __restrict__ labels, float* __restrict__ counts,
                        int M) {
  __shared__ int c[K_CL];
  const int t = threadIdx.x;
  if (t < K_CL) c[t] = 0;
  __syncthreads();
  for (int i = blockIdx.x * blockDim.x + t; i < M; i += gridDim.x * blockDim.x)
    atomicAdd(&c[labels[i]], 1);
  __syncthreads();
  if (t < K_CL && c[t] > 0) atomicAdd(&counts[t], (float)c[t]);
}

// ---------------- K4: segment sum (cols sliced 8-way), optional argmax -----
// labels != nullptr: use labels.  labels == nullptr: argmax over dist[r][0..127].
__launch_bounds__(256)
__global__ void k_segsum(const float* __restrict__ z, const int* __restrict__ labels,
                         const float* __restrict__ dist, float* __restrict__ sums,
                         int M) {
  __shared__ float acc[K_CL][64];
  const int t = threadIdx.x;
  const int w = t >> 6, lane = t & 63;
  for (int i = t; i < K_CL * 64; i += 256) ((float*)acc)[i] = 0.f;
  __syncthreads();
  const int col0 = blockIdx.y * 64;
  const int step = gridDim.x * 4;
  for (int r = blockIdx.x * 4 + w; r < M; r += step) {
    int lab;
    if (labels) {
      lab = labels[r];
    } else {
      const float* dr = dist + (size_t)r * K_CL;
      float v = dr[lane]; int bi = lane;
      float v2 = dr[64 + lane];
      if (v2 > v) { v = v2; bi = 64 + lane; }   // strict >: first index wins
#pragma unroll
      for (int msk = 1; msk < 64; msk <<= 1) {
        float ov = __shfl_xor(v, msk);
        int   oi = __shfl_xor(bi, msk);
        if (ov > v || (ov == v && oi < bi)) { v = ov; bi = oi; }
      }
      lab = bi;
    }
    atomicAdd(&acc[lab][lane], z[(size_t)r * D_DIM + col0 + lane]);
  }
  __syncthreads();
  for (int i = t; i < K_CL * 64; i += 256) {
    int kk = i >> 6, cc = i & 63;
    float s = acc[kk][cc];
    if (s != 0.f) atomicAdd(&sums[(size_t)kk * D_DIM + col0 + cc], s);
  }
}

// ---------------- K5: divide segment sums by counts (in place) -------------
__global__ void k_div(float* __restrict__ buf, const float* __restrict__ counts) {
  const int i = blockIdx.x * 256 + threadIdx.x;   // 65536 total
  buf[i] = buf[i] / fmaxf(counts[i >> 9], 1.0f);
}

// ---------------- K6: dist = z @ mu^T, softmax -> r, argmax, counts --------
// BM=64, N=128 (all clusters), BK=32, 256 threads, 4x8 per thread.
__launch_bounds__(256)
__global__ void k_dist(const float* __restrict__ z, const float* __restrict__ mu,
                       float* __restrict__ dist, float* __restrict__ rr,
                       int* __restrict__ assign, float* __restrict__ countsB,
                       int M) {
  __shared__ float Zs[32][68];     // [k][m]
  __shared__ float Ms[32][132];    // [k][n]  (mu transposed)
  __shared__ int cnt[K_CL];
  const int t  = threadIdx.x;
  const int tx = t & 15, ty = t >> 4;
  const int m0 = blockIdx.x * 64;
  if (t < K_CL) cnt[t] = 0;
  float acc[4][8] = {};
  for (int k0 = 0; k0 < D_DIM; k0 += 32) {
#pragma unroll
    for (int i = 0; i < 2; ++i) {
      int c = t + i * 256;
      int r = c >> 3, kc = (c & 7) << 2;
      float4 v = make_float4(0.f, 0.f, 0.f, 0.f);
      if (m0 + r < M)
        v = *(const float4*)(z + (size_t)(m0 + r) * D_DIM + k0 + kc);
      Zs[kc + 0][r] = v.x; Zs[kc + 1][r] = v.y;
      Zs[kc + 2][r] = v.z; Zs[kc + 3][r] = v.w;
    }
#pragma unroll
    for (int i = 0; i < 4; ++i) {
      int c = t + i * 256;
      int n = c >> 3, kc = (c & 7) << 2;
      float4 v = *(const float4*)(mu + (size_t)n * D_DIM + k0 + kc);
      Ms[kc + 0][n] = v.x; Ms[kc + 1][n] = v.y;
      Ms[kc + 2][n] = v.z; Ms[kc + 3][n] = v.w;
    }
    __syncthreads();
#pragma unroll
    for (int kk = 0; kk < 32; ++kk) {
      float4 av = *(const float4*)&Zs[kk][ty * 4];
      float4 b0 = *(const float4*)&Ms[kk][tx * 8];
      float4 b1 = *(const float4*)&Ms[kk][tx * 8 + 4];
      float a[4] = {av.x, av.y, av.z, av.w};
      float b[8] = {b0.x, b0.y, b0.z, b0.w, b1.x, b1.y, b1.z, b1.w};
#pragma unroll
      for (int i = 0; i < 4; ++i)
#pragma unroll
        for (int j = 0; j < 8; ++j)
          acc[i][j] = fmaf(a[i], b[j], acc[i][j]);
    }
    __syncthreads();
  }
  // per-row: softmax over 128 (16 lanes x 8 each), argmax, stores
#pragma unroll
  for (int i = 0; i < 4; ++i) {
    const int row = m0 + ty * 4 + i;
    float d[8];
#pragma unroll
    for (int j = 0; j < 8; ++j) d[j] = acc[i][j];
    float mx = d[0];
#pragma unroll
    for (int j = 1; j < 8; ++j) mx = fmaxf(mx, d[j]);
#pragma unroll
    for (int msk = 1; msk < 16; msk <<= 1) mx = fmaxf(mx, __shfl_xor(mx, msk));
    float e[8], s = 0.f;
#pragma unroll
    for (int j = 0; j < 8; ++j) { e[j] = __expf(TEMP * (d[j] - mx)); s += e[j]; }
#pragma unroll
    for (int msk = 1; msk < 16; msk <<= 1) s += __shfl_xor(s, msk);
    const float inv = 1.f / s;
    float bv = d[0]; int bi = tx * 8;
#pragma unroll
    for (int j = 1; j < 8; ++j)
      if (d[j] > bv) { bv = d[j]; bi = tx * 8 + j; }
#pragma unroll
    for (int msk = 1; msk < 16; msk <<= 1) {
      float ov = __shfl_xor(bv, msk);
      int   oi = __shfl_xor(bi, msk);
      if (ov > bv || (ov == bv && oi < bi)) { bv = ov; bi = oi; }
    }
    if (row < M) {
      float* dp = dist + (size_t)row * K_CL + tx * 8;
      *(float4*)dp       = make_float4(d[0], d[1], d[2], d[3]);
      *(float4*)(dp + 4) = make_float4(d[4], d[5], d[6], d[7]);
      float* rp = rr + (size_t)row * K_CL + tx * 8;
      *(float4*)rp       = make_float4(e[0]*inv, e[1]*inv, e[2]*inv, e[3]*inv);
      *(float4*)(rp + 4) = make_float4(e[4]*inv, e[5]*inv, e[6]*inv, e[7]*inv);
      if (tx == 0) {
        atomicAdd(&cnt[bi], 1);
        if (assign) assign[row] = bi;
      }
    }
  }
  __syncthreads();
  if (t < K_CL && cnt[t] > 0) atomicAdd(&countsB[t], (float)cnt[t]);
}

// ---------------------------------------------------------------------------
extern "C" void kernel_launch(void* const* d_in, const int* in_sizes, int n_in,
                              void* d_out, int out_size, void* d_ws, size_t ws_size,
                              hipStream_t stream) {
  const float* x      = (const float*)d_in[0];
  const float* w      = (const float*)d_in[1];
  const int*   labels = (const int*)d_in[2];
  float* out = (float*)d_out;

  const int M = in_sizes[0] / D_DIM;          // 100000
  const size_t MD = (size_t)M * D_DIM;
  const size_t MK = (size_t)M * K_CL;

  float* posz = out;                   // [M,512]
  float* mu   = out + MD;              // [128,512]
  float* rr   = mu + (size_t)K_CL * D_DIM;   // [M,128]
  float* dist = rr + MK;               // [M,128]
  float* u    = dist + MK;             // [128,512]

  float* countsA = (float*)d_ws;       // 128 f32
  float* countsB = countsA + K_CL;     // 128 f32
  int* assign = (ws_size >= 1024 + (size_t)M * 4)
                    ? (int*)((char*)d_ws + 1024) : nullptr;

  hipMemsetAsync(mu, 0, (size_t)K_CL * D_DIM * sizeof(float), stream);
  hipMemsetAsync(u,  0, (size_t)K_CL * D_DIM * sizeof(float), stream);
  hipMemsetAsync(d_ws, 0, 1024, stream);

  k_gemm<<<dim3((M + 127) / 128, 4), 256, 0, stream>>>(x, w, posz, M);
  k_norm<<<(M + 3) / 4, 256, 0, stream>>>(posz, M);
  k_count<<<256, 256, 0, stream>>>(labels, countsA, M);
  k_segsum<<<dim3(128, 8), 256, 0, stream>>>(posz, labels, nullptr, mu, M);
  k_div<<<256, 256, 0, stream>>>(mu, countsA);
  k_dist<<<(M + 63) / 64, 256, 0, stream>>>(posz, mu, dist, rr, assign, countsB, M);
  k_segsum<<<dim3(128, 8), 256, 0, stream>>>(posz, assign, dist, u, M);
  k_div<<<256, 256, 0, stream>>>(u, countsB);
}

// Round 2
// 1286.801 us; speedup vs baseline: 1.3488x; 1.3488x over previous
//
#include <hip/hip_runtime.h>
#include <hip/hip_fp16.h>

#define D_DIM 512
#define K_CL  128
#define TEMP  30.0f

typedef _Float16 half8  __attribute__((ext_vector_type(8)));
typedef _Float16 half4v __attribute__((ext_vector_type(4)));
typedef float    floatx4 __attribute__((ext_vector_type(4)));

#define MFMA16(a, b, c) __builtin_amdgcn_mfma_f32_16x16x32_f16((a), (b), (c), 0, 0, 0)

__device__ __forceinline__ void gload_lds16(const void* g, void* l) {
  __builtin_amdgcn_global_load_lds(
      (const __attribute__((address_space(1))) void*)g,
      (__attribute__((address_space(3))) void*)l, 16, 0, 0);
}

// ---------------- K0: split W (f32) -> Wg (f16 hi/lo) in staging order -----
// Wg layout: [ks(16)][sel(2: hi,lo)][kc(4)][n(512)][j(8)]  (element k = ks*32+kc*8+j)
__global__ void k_wsplit(const float* __restrict__ w, _Float16* __restrict__ wg) {
  const int idx = blockIdx.x * 256 + threadIdx.x;   // 0..262143
  const int k = idx >> 9, n = idx & 511;
  const float v = w[idx];
  const _Float16 hi = (_Float16)v;
  const _Float16 lo = (_Float16)(v - (float)hi);
  const int ks = k >> 5, kc = (k >> 3) & 3, j = k & 7;
  const size_t base = (size_t)ks * 32768 + (size_t)kc * 4096 + (size_t)n * 8 + j;
  wg[base]         = hi;
  wg[base + 16384] = lo;
}

// ---------------- K1: pos_z = rownorm(x @ W), split-f16 MFMA ---------------
// BM=64, BN=512 (full row), BK=32. 512 threads = 8 waves; wave w owns cols
// [w*64, w*64+64). Per wave: 4x4 frags of 16x16 (acc 64 f32/lane).
__launch_bounds__(512, 4)
__global__ void k_gemm(const float* __restrict__ x, const _Float16* __restrict__ wg,
                       float* __restrict__ posz, int M) {
  __shared__ _Float16 Bs[32768];            // [sel][kc][n][8]  = 64 KiB
  __shared__ _Float16 AsH[4 * 520];         // [kc][m(64)][8], kc-stride padded
  __shared__ _Float16 AsL[4 * 520];
  __shared__ float ssqLds[64][9];
  __shared__ float invLds[64];

  const int t    = threadIdx.x;
  const int w    = t >> 6;
  const int lane = t & 63;
  const int hi4  = lane >> 4;
  const int l15  = lane & 15;
  const int m0   = blockIdx.x * 64;

  // A staging map: thread t -> row ar (0..63), 4 cols at ac4
  const int ar  = t >> 3;
  const int ac4 = (t & 7) << 2;
  const int akc = ac4 >> 3;
  const int aj  = ac4 & 7;
  const size_t xrow  = (size_t)(m0 + ar) * D_DIM;
  const bool arow_ok = (m0 + ar) < M;

  floatx4 acc[4][4] = {};

  for (int ks = 0; ks < 16; ++ks) {
    // --- stage B: 64KB via global_load_lds (coalesced, linear dest) ---
    const _Float16* gb = wg + (size_t)ks * 32768;
#pragma unroll
    for (int i = 0; i < 8; ++i)
      gload_lds16(gb + (size_t)(i * 512 + t) * 8, &Bs[(i * 512 + (w << 6)) * 8]);
    // --- stage A: load f32, split to f16 hi/lo, ds_write ---
    float4 v = make_float4(0.f, 0.f, 0.f, 0.f);
    if (arow_ok) v = *(const float4*)(x + xrow + (ks << 5) + ac4);
    half4v h, l;
    h.x = (_Float16)v.x; l.x = (_Float16)(v.x - (float)h.x);
    h.y = (_Float16)v.y; l.y = (_Float16)(v.y - (float)h.y);
    h.z = (_Float16)v.z; l.z = (_Float16)(v.z - (float)h.z);
    h.w = (_Float16)v.w; l.w = (_Float16)(v.w - (float)h.w);
    *(half4v*)&AsH[akc * 520 + ar * 8 + aj] = h;
    *(half4v*)&AsL[akc * 520 + ar * 8 + aj] = l;
    __syncthreads();
    // --- compute: 48 MFMA / wave / k-step ---
#pragma unroll
    for (int mf = 0; mf < 4; ++mf) {
      const int aoff = hi4 * 520 + (mf * 16 + l15) * 8;
      half8 ah = *(const half8*)&AsH[aoff];
      half8 al = *(const half8*)&AsL[aoff];
#pragma unroll
      for (int nf = 0; nf < 4; ++nf) {
        const int bo = hi4 * 4096 + ((w << 6) + nf * 16 + l15) * 8;
        half8 bh = *(const half8*)&Bs[bo];
        half8 bl = *(const half8*)&Bs[bo + 16384];
        acc[mf][nf] = MFMA16(ah, bh, acc[mf][nf]);
        acc[mf][nf] = MFMA16(ah, bl, acc[mf][nf]);
        acc[mf][nf] = MFMA16(al, bh, acc[mf][nf]);
      }
    }
    __syncthreads();
  }

  // --- fused row L2-norm epilogue ---
  // lane holds rows rl = mf*16 + hi4*4 + r, cols w*64 + nf*16 + l15
  float sp[16];
#pragma unroll
  for (int mf = 0; mf < 4; ++mf)
#pragma unroll
    for (int r = 0; r < 4; ++r) {
      float s = 0.f;
#pragma unroll
      for (int nf = 0; nf < 4; ++nf) { float vv = acc[mf][nf][r]; s += vv * vv; }
      sp[mf * 4 + r] = s;
    }
#pragma unroll
  for (int msk = 1; msk < 16; msk <<= 1)
#pragma unroll
    for (int i = 0; i < 16; ++i) sp[i] += __shfl_xor(sp[i], msk);
  if (l15 == 0) {
#pragma unroll
    for (int mf = 0; mf < 4; ++mf)
#pragma unroll
      for (int r = 0; r < 4; ++r)
        ssqLds[mf * 16 + hi4 * 4 + r][w] = sp[mf * 4 + r];
  }
  __syncthreads();
  if (t < 64) {
    float s = 0.f;
#pragma unroll
    for (int i = 0; i < 8; ++i) s += ssqLds[t][i];
    invLds[t] = rsqrtf(s);
  }
  __syncthreads();
#pragma unroll
  for (int mf = 0; mf < 4; ++mf)
#pragma unroll
    for (int r = 0; r < 4; ++r) {
      const int rl = mf * 16 + hi4 * 4 + r;
      if (m0 + rl < M) {
        const float iv = invLds[rl];
        float* pz = posz + (size_t)(m0 + rl) * D_DIM + (w << 6) + l15;
#pragma unroll
        for (int nf = 0; nf < 4; ++nf) pz[nf * 16] = acc[mf][nf][r] * iv;
      }
    }
}

// ---------------- K3: histogram of comm_labels -> counts (float) -----------
__global__ void k_count(const int* __restrict__ labels, float* __restrict__ counts,
                        int M) {
  __shared__ int c[K_CL];
  const int t = threadIdx.x;
  if (t < K_CL) c[t] = 0;
  __syncthreads();
  for (int i = blockIdx.x * blockDim.x + t; i < M; i += gridDim.x * blockDim.x)
    atomicAdd(&c[labels[i]], 1);
  __syncthreads();
  if (t < K_CL && c[t] > 0) atomicAdd(&counts[t], (float)c[t]);
}

// ---------------- K4: segment sum (cols sliced 8-way), optional argmax -----
__launch_bounds__(256)
__global__ void k_segsum(const float* __restrict__ z, const int* __restrict__ labels,
                         const float* __restrict__ dist, float* __restrict__ sums,
                         int M) {
  __shared__ float acc[K_CL][64];
  const int t = threadIdx.x;
  const int w = t >> 6, lane = t & 63;
  for (int i = t; i < K_CL * 64; i += 256) ((float*)acc)[i] = 0.f;
  __syncthreads();
  const int col0 = blockIdx.y * 64;
  const int step = gridDim.x * 4;
  for (int r = blockIdx.x * 4 + w; r < M; r += step) {
    int lab;
    if (labels) {
      lab = labels[r];
    } else {
      const float* dr = dist + (size_t)r * K_CL;
      float v = dr[lane]; int bi = lane;
      float v2 = dr[64 + lane];
      if (v2 > v) { v = v2; bi = 64 + lane; }
#pragma unroll
      for (int msk = 1; msk < 64; msk <<= 1) {
        float ov = __shfl_xor(v, msk);
        int   oi = __shfl_xor(bi, msk);
        if (ov > v || (ov == v && oi < bi)) { v = ov; bi = oi; }
      }
      lab = bi;
    }
    atomicAdd(&acc[lab][lane], z[(size_t)r * D_DIM + col0 + lane]);
  }
  __syncthreads();
  for (int i = t; i < K_CL * 64; i += 256) {
    int kk = i >> 6, cc = i & 63;
    float s = acc[kk][cc];
    if (s != 0.f) atomicAdd(&sums[(size_t)kk * D_DIM + col0 + cc], s);
  }
}

// ---------------- K5: divide segment sums by counts (in place) -------------
__global__ void k_div(float* __restrict__ buf, const float* __restrict__ counts) {
  const int i = blockIdx.x * 256 + threadIdx.x;   // 65536 total
  buf[i] = buf[i] / fmaxf(counts[i >> 9], 1.0f);
}

// ---------------- K6: dist = z @ mu^T, softmax -> r, argmax, counts --------
__launch_bounds__(256)
__global__ void k_dist(const float* __restrict__ z, const float* __restrict__ mu,
                       float* __restrict__ dist, float* __restrict__ rr,
                       int* __restrict__ assign, float* __restrict__ countsB,
                       int M) {
  __shared__ float Zs[32][68];
  __shared__ float Ms[32][132];
  __shared__ int cnt[K_CL];
  const int t  = threadIdx.x;
  const int tx = t & 15, ty = t >> 4;
  const int m0 = blockIdx.x * 64;
  if (t < K_CL) cnt[t] = 0;
  float acc[4][8] = {};
  for (int k0 = 0; k0 < D_DIM; k0 += 32) {
#pragma unroll
    for (int i = 0; i < 2; ++i) {
      int c = t + i * 256;
      int r = c >> 3, kc = (c & 7) << 2;
      float4 v = make_float4(0.f, 0.f, 0.f, 0.f);
      if (m0 + r < M)
        v = *(const float4*)(z + (size_t)(m0 + r) * D_DIM + k0 + kc);
      Zs[kc + 0][r] = v.x; Zs[kc + 1][r] = v.y;
      Zs[kc + 2][r] = v.z; Zs[kc + 3][r] = v.w;
    }
#pragma unroll
    for (int i = 0; i < 4; ++i) {
      int c = t + i * 256;
      int n = c >> 3, kc = (c & 7) << 2;
      float4 v = *(const float4*)(mu + (size_t)n * D_DIM + k0 + kc);
      Ms[kc + 0][n] = v.x; Ms[kc + 1][n] = v.y;
      Ms[kc + 2][n] = v.z; Ms[kc + 3][n] = v.w;
    }
    __syncthreads();
#pragma unroll
    for (int kk = 0; kk < 32; ++kk) {
      float4 av = *(const float4*)&Zs[kk][ty * 4];
      float4 b0 = *(const float4*)&Ms[kk][tx * 8];
      float4 b1 = *(const float4*)&Ms[kk][tx * 8 + 4];
      float a[4] = {av.x, av.y, av.z, av.w};
      float b[8] = {b0.x, b0.y, b0.z, b0.w, b1.x, b1.y, b1.z, b1.w};
#pragma unroll
      for (int i = 0; i < 4; ++i)
#pragma unroll
        for (int j = 0; j < 8; ++j)
          acc[i][j] = fmaf(a[i], b[j], acc[i][j]);
    }
    __syncthreads();
  }
#pragma unroll
  for (int i = 0; i < 4; ++i) {
    const int row = m0 + ty * 4 + i;
    float d[8];
#pragma unroll
    for (int j = 0; j < 8; ++j) d[j] = acc[i][j];
    float mx = d[0];
#pragma unroll
    for (int j = 1; j < 8; ++j) mx = fmaxf(mx, d[j]);
#pragma unroll
    for (int msk = 1; msk < 16; msk <<= 1) mx = fmaxf(mx, __shfl_xor(mx, msk));
    float e[8], s = 0.f;
#pragma unroll
    for (int j = 0; j < 8; ++j) { e[j] = __expf(TEMP * (d[j] - mx)); s += e[j]; }
#pragma unroll
    for (int msk = 1; msk < 16; msk <<= 1) s += __shfl_xor(s, msk);
    const float inv = 1.f / s;
    float bv = d[0]; int bi = tx * 8;
#pragma unroll
    for (int j = 1; j < 8; ++j)
      if (d[j] > bv) { bv = d[j]; bi = tx * 8 + j; }
#pragma unroll
    for (int msk = 1; msk < 16; msk <<= 1) {
      float ov = __shfl_xor(bv, msk);
      int   oi = __shfl_xor(bi, msk);
      if (ov > bv || (ov == bv && oi < bi)) { bv = ov; bi = oi; }
    }
    if (row < M) {
      float* dp = dist + (size_t)row * K_CL + tx * 8;
      *(float4*)dp       = make_float4(d[0], d[1], d[2], d[3]);
      *(float4*)(dp + 4) = make_float4(d[4], d[5], d[6], d[7]);
      float* rp = rr + (size_t)row * K_CL + tx * 8;
      *(float4*)rp       = make_float4(e[0]*inv, e[1]*inv, e[2]*inv, e[3]*inv);
      *(float4*)(rp + 4) = make_float4(e[4]*inv, e[5]*inv, e[6]*inv, e[7]*inv);
      if (tx == 0) {
        atomicAdd(&cnt[bi], 1);
        if (assign) assign[row] = bi;
      }
    }
  }
  __syncthreads();
  if (t < K_CL && cnt[t] > 0) atomicAdd(&countsB[t], (float)cnt[t]);
}

// ---------------------------------------------------------------------------
extern "C" void kernel_launch(void* const* d_in, const int* in_sizes, int n_in,
                              void* d_out, int out_size, void* d_ws, size_t ws_size,
                              hipStream_t stream) {
  const float* x      = (const float*)d_in[0];
  const float* w      = (const float*)d_in[1];
  const int*   labels = (const int*)d_in[2];
  float* out = (float*)d_out;

  const int M = in_sizes[0] / D_DIM;          // 100000
  const size_t MD = (size_t)M * D_DIM;
  const size_t MK = (size_t)M * K_CL;

  float* posz = out;                         // [M,512]
  float* mu   = out + MD;                    // [128,512]
  float* rr   = mu + (size_t)K_CL * D_DIM;   // [M,128]
  float* dist = rr + MK;                     // [M,128]
  float* u    = dist + MK;                   // [128,512]

  // W split (1 MB) parked in the rr output region (unused until k_dist).
  _Float16* wg = (_Float16*)rr;

  float* countsA = (float*)d_ws;             // 128 f32
  float* countsB = countsA + K_CL;           // 128 f32
  int* assign = (ws_size >= 1024 + (size_t)M * 4)
                    ? (int*)((char*)d_ws + 1024) : nullptr;

  hipMemsetAsync(mu, 0, (size_t)K_CL * D_DIM * sizeof(float), stream);
  hipMemsetAsync(u,  0, (size_t)K_CL * D_DIM * sizeof(float), stream);
  hipMemsetAsync(d_ws, 0, 1024, stream);

  k_wsplit<<<1024, 256, 0, stream>>>(w, wg);
  k_gemm<<<(M + 63) / 64, 512, 0, stream>>>(x, wg, posz, M);
  k_count<<<256, 256, 0, stream>>>(labels, countsA, M);
  k_segsum<<<dim3(128, 8), 256, 0, stream>>>(posz, labels, nullptr, mu, M);
  k_div<<<256, 256, 0, stream>>>(mu, countsA);
  k_dist<<<(M + 63) / 64, 256, 0, stream>>>(posz, mu, dist, rr, assign, countsB, M);
  k_segsum<<<dim3(128, 8), 256, 0, stream>>>(posz, assign, dist, u, M);
  k_div<<<256, 256, 0, stream>>>(u, countsB);
}

// Round 3
// 849.474 us; speedup vs baseline: 2.0431x; 1.5148x over previous
//
#include <hip/hip_runtime.h>
#include <hip/hip_fp16.h>

#define D_DIM 512
#define K_CL  128
#define TEMP  30.0f

typedef _Float16 half8  __attribute__((ext_vector_type(8)));
typedef _Float16 half4v __attribute__((ext_vector_type(4)));
typedef float    floatx4 __attribute__((ext_vector_type(4)));

#define MFMA16(a, b, c) __builtin_amdgcn_mfma_f32_16x16x32_f16((a), (b), (c), 0, 0, 0)

__device__ __forceinline__ void gload_lds16(const void* g, void* l) {
  __builtin_amdgcn_global_load_lds(
      (const __attribute__((address_space(1))) void*)g,
      (__attribute__((address_space(3))) void*)l, 16, 0, 0);
}

// ---------------- K0: split W (f32) -> Wg (f16 hi/lo) in staging order -----
// Wg layout: [ks(16)][sel(2: hi,lo)][kc(4)][n(512)][j(8)]  (element k = ks*32+kc*8+j)
__global__ void k_wsplit(const float* __restrict__ w, _Float16* __restrict__ wg) {
  const int idx = blockIdx.x * 256 + threadIdx.x;   // 0..262143
  const int k = idx >> 9, n = idx & 511;
  const float v = w[idx];
  const _Float16 hi = (_Float16)v;
  const _Float16 lo = (_Float16)(v - (float)hi);
  const int ks = k >> 5, kc = (k >> 3) & 3, j = k & 7;
  const size_t base = (size_t)ks * 32768 + (size_t)kc * 4096 + (size_t)n * 8 + j;
  wg[base]         = hi;
  wg[base + 16384] = lo;
}

// ---------------- K1: pos_z = rownorm(x @ W), split-f16 MFMA ---------------
__launch_bounds__(512, 4)
__global__ void k_gemm(const float* __restrict__ x, const _Float16* __restrict__ wg,
                       float* __restrict__ posz, int M) {
  __shared__ _Float16 Bs[32768];            // 64 KiB
  __shared__ _Float16 AsH[4 * 520];
  __shared__ _Float16 AsL[4 * 520];
  __shared__ float ssqLds[64][9];
  __shared__ float invLds[64];

  const int t    = threadIdx.x;
  const int w    = t >> 6;
  const int lane = t & 63;
  const int hi4  = lane >> 4;
  const int l15  = lane & 15;
  const int m0   = blockIdx.x * 64;

  const int ar  = t >> 3;
  const int ac4 = (t & 7) << 2;
  const int akc = ac4 >> 3;
  const int aj  = ac4 & 7;
  const size_t xrow  = (size_t)(m0 + ar) * D_DIM;
  const bool arow_ok = (m0 + ar) < M;

  floatx4 acc[4][4] = {};

  for (int ks = 0; ks < 16; ++ks) {
    const _Float16* gb = wg + (size_t)ks * 32768;
#pragma unroll
    for (int i = 0; i < 8; ++i)
      gload_lds16(gb + (size_t)(i * 512 + t) * 8, &Bs[(i * 512 + (w << 6)) * 8]);
    float4 v = make_float4(0.f, 0.f, 0.f, 0.f);
    if (arow_ok) v = *(const float4*)(x + xrow + (ks << 5) + ac4);
    half4v h, l;
    h.x = (_Float16)v.x; l.x = (_Float16)(v.x - (float)h.x);
    h.y = (_Float16)v.y; l.y = (_Float16)(v.y - (float)h.y);
    h.z = (_Float16)v.z; l.z = (_Float16)(v.z - (float)h.z);
    h.w = (_Float16)v.w; l.w = (_Float16)(v.w - (float)h.w);
    *(half4v*)&AsH[akc * 520 + ar * 8 + aj] = h;
    *(half4v*)&AsL[akc * 520 + ar * 8 + aj] = l;
    __syncthreads();
#pragma unroll
    for (int mf = 0; mf < 4; ++mf) {
      const int aoff = hi4 * 520 + (mf * 16 + l15) * 8;
      half8 ah = *(const half8*)&AsH[aoff];
      half8 al = *(const half8*)&AsL[aoff];
#pragma unroll
      for (int nf = 0; nf < 4; ++nf) {
        const int bo = hi4 * 4096 + ((w << 6) + nf * 16 + l15) * 8;
        half8 bh = *(const half8*)&Bs[bo];
        half8 bl = *(const half8*)&Bs[bo + 16384];
        acc[mf][nf] = MFMA16(ah, bh, acc[mf][nf]);
        acc[mf][nf] = MFMA16(ah, bl, acc[mf][nf]);
        acc[mf][nf] = MFMA16(al, bh, acc[mf][nf]);
      }
    }
    __syncthreads();
  }

  float sp[16];
#pragma unroll
  for (int mf = 0; mf < 4; ++mf)
#pragma unroll
    for (int r = 0; r < 4; ++r) {
      float s = 0.f;
#pragma unroll
      for (int nf = 0; nf < 4; ++nf) { float vv = acc[mf][nf][r]; s += vv * vv; }
      sp[mf * 4 + r] = s;
    }
#pragma unroll
  for (int msk = 1; msk < 16; msk <<= 1)
#pragma unroll
    for (int i = 0; i < 16; ++i) sp[i] += __shfl_xor(sp[i], msk);
  if (l15 == 0) {
#pragma unroll
    for (int mf = 0; mf < 4; ++mf)
#pragma unroll
      for (int r = 0; r < 4; ++r)
        ssqLds[mf * 16 + hi4 * 4 + r][w] = sp[mf * 4 + r];
  }
  __syncthreads();
  if (t < 64) {
    float s = 0.f;
#pragma unroll
    for (int i = 0; i < 8; ++i) s += ssqLds[t][i];
    invLds[t] = rsqrtf(s);
  }
  __syncthreads();
#pragma unroll
  for (int mf = 0; mf < 4; ++mf)
#pragma unroll
    for (int r = 0; r < 4; ++r) {
      const int rl = mf * 16 + hi4 * 4 + r;
      if (m0 + rl < M) {
        const float iv = invLds[rl];
        float* pz = posz + (size_t)(m0 + rl) * D_DIM + (w << 6) + l15;
#pragma unroll
        for (int nf = 0; nf < 4; ++nf) pz[nf * 16] = acc[mf][nf][r] * iv;
      }
    }
}

// ---------------- K3: int histogram of labels --------------------------------
__global__ void k_count(const int* __restrict__ labels, int* __restrict__ counts,
                        int M) {
  __shared__ int c[K_CL];
  const int t = threadIdx.x;
  if (t < K_CL) c[t] = 0;
  __syncthreads();
  for (int i = blockIdx.x * blockDim.x + t; i < M; i += gridDim.x * blockDim.x)
    atomicAdd(&c[labels[i]], 1);
  __syncthreads();
  if (t < K_CL && c[t] > 0) atomicAdd(&counts[t], c[t]);
}

// ---------------- K3b: exclusive scan of 128 counts (1 block, 128 thr) ------
__global__ void k_scan(const int* __restrict__ cnt, int* __restrict__ off,
                       int* __restrict__ cursor) {
  __shared__ int s[K_CL];
  const int t = threadIdx.x;
  const int c = cnt[t];
  s[t] = c;
  __syncthreads();
  for (int d = 1; d < K_CL; d <<= 1) {
    int v = (t >= d) ? s[t - d] : 0;
    __syncthreads();
    s[t] += v;
    __syncthreads();
  }
  const int excl = s[t] - c;
  off[t] = excl;
  cursor[t] = excl;
}

// ---------------- K3c: scatter row indices grouped by label ------------------
__launch_bounds__(256)
__global__ void k_scatter(const int* __restrict__ labels, int* __restrict__ cursor,
                          int* __restrict__ perm, int M) {
  __shared__ int lhist[K_CL], lbase[K_CL], lpos[K_CL];
  const int t = threadIdx.x;
  const int r0 = blockIdx.x * 1024;
  if (t < K_CL) { lhist[t] = 0; lpos[t] = 0; }
  __syncthreads();
  int labv[4], rv[4];
#pragma unroll
  for (int j = 0; j < 4; ++j) {
    const int r = r0 + j * 256 + t;
    rv[j] = r;
    labv[j] = (r < M) ? labels[r] : -1;
    if (labv[j] >= 0) atomicAdd(&lhist[labv[j]], 1);
  }
  __syncthreads();
  if (t < K_CL && lhist[t] > 0) lbase[t] = atomicAdd(&cursor[t], lhist[t]);
  __syncthreads();
#pragma unroll
  for (int j = 0; j < 4; ++j)
    if (labv[j] >= 0) {
      const int p = atomicAdd(&lpos[labv[j]], 1);
      perm[lbase[labv[j]] + p] = rv[j];
    }
}

// ---------------- K4: sorted gather segment-mean (no atomics) ----------------
// grid (K_CL labels, 8 slices of 64 cols), 256 threads: 16 row-streams x 16 f4cols.
__launch_bounds__(256)
__global__ void k_segmean(const float* __restrict__ z, const int* __restrict__ perm,
                          const int* __restrict__ off, const int* __restrict__ cnt,
                          float* __restrict__ out) {
  __shared__ int pl[2048];
  __shared__ float red[16][68];
  const int t    = threadIdx.x;
  const int lab  = blockIdx.x;
  const int c0   = blockIdx.y * 64;
  const int rowg = t >> 4;            // 0..15
  const int c4   = (t & 15) << 2;     // float index 0..60
  const int start = off[lab];
  const int n     = cnt[lab];
  float4 acc = make_float4(0.f, 0.f, 0.f, 0.f);
  for (int tile = 0; tile < n; tile += 2048) {
    const int tn = min(2048, n - tile);
    __syncthreads();
    for (int i = t; i < tn; i += 256) pl[i] = perm[start + tile + i];
    __syncthreads();
    for (int i = rowg; i < tn; i += 16) {
      const int r = pl[i];
      const float4 v = *(const float4*)(z + (size_t)r * D_DIM + c0 + c4);
      acc.x += v.x; acc.y += v.y; acc.z += v.z; acc.w += v.w;
    }
  }
  __syncthreads();
  *(float4*)&red[rowg][c4] = acc;
  __syncthreads();
  if (t < 64) {
    float s = 0.f;
#pragma unroll
    for (int g = 0; g < 16; ++g) s += red[g][t];
    out[(size_t)lab * D_DIM + c0 + t] = s / fmaxf((float)n, 1.0f);
  }
}

// ---------------- K4f: fallback segment sum (round-2 path) -------------------
__launch_bounds__(256)
__global__ void k_segsum(const float* __restrict__ z, const int* __restrict__ labels,
                         const float* __restrict__ dist, float* __restrict__ sums,
                         int M) {
  __shared__ float acc[K_CL][64];
  const int t = threadIdx.x;
  const int w = t >> 6, lane = t & 63;
  for (int i = t; i < K_CL * 64; i += 256) ((float*)acc)[i] = 0.f;
  __syncthreads();
  const int col0 = blockIdx.y * 64;
  const int step = gridDim.x * 4;
  for (int r = blockIdx.x * 4 + w; r < M; r += step) {
    int lab;
    if (labels) {
      lab = labels[r];
    } else {
      const float* dr = dist + (size_t)r * K_CL;
      float v = dr[lane]; int bi = lane;
      float v2 = dr[64 + lane];
      if (v2 > v) { v = v2; bi = 64 + lane; }
#pragma unroll
      for (int msk = 1; msk < 64; msk <<= 1) {
        float ov = __shfl_xor(v, msk);
        int   oi = __shfl_xor(bi, msk);
        if (ov > v || (ov == v && oi < bi)) { v = ov; bi = oi; }
      }
      lab = bi;
    }
    atomicAdd(&acc[lab][lane], z[(size_t)r * D_DIM + col0 + lane]);
  }
  __syncthreads();
  for (int i = t; i < K_CL * 64; i += 256) {
    int kk = i >> 6, cc = i & 63;
    float s = acc[kk][cc];
    if (s != 0.f) atomicAdd(&sums[(size_t)kk * D_DIM + col0 + cc], s);
  }
}

// ---------------- K5: fallback divide by counts ------------------------------
__global__ void k_div(float* __restrict__ buf, const int* __restrict__ counts) {
  const int i = blockIdx.x * 256 + threadIdx.x;   // 65536 total
  buf[i] = buf[i] / fmaxf((float)counts[i >> 9], 1.0f);
}

// ---------------- K6: dist = z @ mu^T, softmax -> r, argmax, counts ----------
__launch_bounds__(256)
__global__ void k_dist(const float* __restrict__ z, const float* __restrict__ mu,
                       float* __restrict__ dist, float* __restrict__ rr,
                       int* __restrict__ assign, int* __restrict__ countsB,
                       int M) {
  __shared__ float Zs[32][68];
  __shared__ float Ms[32][132];
  __shared__ int cnt[K_CL];
  const int t  = threadIdx.x;
  const int tx = t & 15, ty = t >> 4;
  const int m0 = blockIdx.x * 64;
  if (t < K_CL) cnt[t] = 0;
  float acc[4][8] = {};
  for (int k0 = 0; k0 < D_DIM; k0 += 32) {
#pragma unroll
    for (int i = 0; i < 2; ++i) {
      int c = t + i * 256;
      int r = c >> 3, kc = (c & 7) << 2;
      float4 v = make_float4(0.f, 0.f, 0.f, 0.f);
      if (m0 + r < M)
        v = *(const float4*)(z + (size_t)(m0 + r) * D_DIM + k0 + kc);
      Zs[kc + 0][r] = v.x; Zs[kc + 1][r] = v.y;
      Zs[kc + 2][r] = v.z; Zs[kc + 3][r] = v.w;
    }
#pragma unroll
    for (int i = 0; i < 4; ++i) {
      int c = t + i * 256;
      int n = c >> 3, kc = (c & 7) << 2;
      float4 v = *(const float4*)(mu + (size_t)n * D_DIM + k0 + kc);
      Ms[kc + 0][n] = v.x; Ms[kc + 1][n] = v.y;
      Ms[kc + 2][n] = v.z; Ms[kc + 3][n] = v.w;
    }
    __syncthreads();
#pragma unroll
    for (int kk = 0; kk < 32; ++kk) {
      float4 av = *(const float4*)&Zs[kk][ty * 4];
      float4 b0 = *(const float4*)&Ms[kk][tx * 8];
      float4 b1 = *(const float4*)&Ms[kk][tx * 8 + 4];
      float a[4] = {av.x, av.y, av.z, av.w};
      float b[8] = {b0.x, b0.y, b0.z, b0.w, b1.x, b1.y, b1.z, b1.w};
#pragma unroll
      for (int i = 0; i < 4; ++i)
#pragma unroll
        for (int j = 0; j < 8; ++j)
          acc[i][j] = fmaf(a[i], b[j], acc[i][j]);
    }
    __syncthreads();
  }
#pragma unroll
  for (int i = 0; i < 4; ++i) {
    const int row = m0 + ty * 4 + i;
    float d[8];
#pragma unroll
    for (int j = 0; j < 8; ++j) d[j] = acc[i][j];
    float mx = d[0];
#pragma unroll
    for (int j = 1; j < 8; ++j) mx = fmaxf(mx, d[j]);
#pragma unroll
    for (int msk = 1; msk < 16; msk <<= 1) mx = fmaxf(mx, __shfl_xor(mx, msk));
    float e[8], s = 0.f;
#pragma unroll
    for (int j = 0; j < 8; ++j) { e[j] = __expf(TEMP * (d[j] - mx)); s += e[j]; }
#pragma unroll
    for (int msk = 1; msk < 16; msk <<= 1) s += __shfl_xor(s, msk);
    const float inv = 1.f / s;
    float bv = d[0]; int bi = tx * 8;
#pragma unroll
    for (int j = 1; j < 8; ++j)
      if (d[j] > bv) { bv = d[j]; bi = tx * 8 + j; }
#pragma unroll
    for (int msk = 1; msk < 16; msk <<= 1) {
      float ov = __shfl_xor(bv, msk);
      int   oi = __shfl_xor(bi, msk);
      if (ov > bv || (ov == bv && oi < bi)) { bv = ov; bi = oi; }
    }
    if (row < M) {
      float* dp = dist + (size_t)row * K_CL + tx * 8;
      *(float4*)dp       = make_float4(d[0], d[1], d[2], d[3]);
      *(float4*)(dp + 4) = make_float4(d[4], d[5], d[6], d[7]);
      float* rp = rr + (size_t)row * K_CL + tx * 8;
      *(float4*)rp       = make_float4(e[0]*inv, e[1]*inv, e[2]*inv, e[3]*inv);
      *(float4*)(rp + 4) = make_float4(e[4]*inv, e[5]*inv, e[6]*inv, e[7]*inv);
      if (tx == 0) {
        if (assign) assign[row] = bi;
        atomicAdd(&cnt[bi], 1);
      }
    }
  }
  __syncthreads();
  if (t < K_CL && cnt[t] > 0) atomicAdd(&countsB[t], cnt[t]);
}

// ---------------------------------------------------------------------------
extern "C" void kernel_launch(void* const* d_in, const int* in_sizes, int n_in,
                              void* d_out, int out_size, void* d_ws, size_t ws_size,
                              hipStream_t stream) {
  const float* x      = (const float*)d_in[0];
  const float* w      = (const float*)d_in[1];
  const int*   labels = (const int*)d_in[2];
  float* out = (float*)d_out;

  const int M = in_sizes[0] / D_DIM;          // 100000
  const size_t MD = (size_t)M * D_DIM;
  const size_t MK = (size_t)M * K_CL;

  float* posz = out;                         // [M,512]
  float* mu   = out + MD;                    // [128,512]
  float* rr   = mu + (size_t)K_CL * D_DIM;   // [M,128]
  float* dist = rr + MK;                     // [M,128]
  float* u    = dist + MK;                   // [128,512]

  // W split (1 MB) parked in the rr output region (unused until k_dist).
  _Float16* wg = (_Float16*)rr;

  // workspace layout
  int* cntA = (int*)d_ws;                  // 128
  int* cntB = cntA + 128;                  // 128
  int* offA = cntA + 256;                  // 128
  int* curA = cntA + 384;                  // 128
  int* offB = cntA + 512;                  // 128
  int* curB = cntA + 640;                  // 128
  int* assign = cntA + 1024;               // M
  int* permA  = assign + M;                // M
  int* permB  = permA + M;                 // M
  const size_t need = 4096 + 3ull * M * 4;

  const int nScatter = (M + 1023) / 1024;

  if (ws_size >= need) {
    // ---- full sorted path: no global atomics in the means ----
    hipMemsetAsync(d_ws, 0, 4096, stream);
    k_wsplit<<<1024, 256, 0, stream>>>(w, wg);
    k_gemm<<<(M + 63) / 64, 512, 0, stream>>>(x, wg, posz, M);
    k_count<<<256, 256, 0, stream>>>(labels, cntA, M);
    k_scan<<<1, 128, 0, stream>>>(cntA, offA, curA);
    k_scatter<<<nScatter, 256, 0, stream>>>(labels, curA, permA, M);
    k_segmean<<<dim3(K_CL, 8), 256, 0, stream>>>(posz, permA, offA, cntA, mu);
    k_dist<<<(M + 63) / 64, 256, 0, stream>>>(posz, mu, dist, rr, assign, cntB, M);
    k_scan<<<1, 128, 0, stream>>>(cntB, offB, curB);
    k_scatter<<<nScatter, 256, 0, stream>>>(assign, curB, permB, M);
    k_segmean<<<dim3(K_CL, 8), 256, 0, stream>>>(posz, permB, offB, cntB, u);
  } else {
    // ---- fallback: round-2 atomic path ----
    int* fb_assign = (ws_size >= 1024 + (size_t)M * 4)
                         ? (int*)((char*)d_ws + 1024) : nullptr;
    hipMemsetAsync(mu, 0, (size_t)K_CL * D_DIM * sizeof(float), stream);
    hipMemsetAsync(u,  0, (size_t)K_CL * D_DIM * sizeof(float), stream);
    hipMemsetAsync(d_ws, 0, 1024, stream);
    k_wsplit<<<1024, 256, 0, stream>>>(w, wg);
    k_gemm<<<(M + 63) / 64, 512, 0, stream>>>(x, wg, posz, M);
    k_count<<<256, 256, 0, stream>>>(labels, cntA, M);
    k_segsum<<<dim3(128, 8), 256, 0, stream>>>(posz, labels, nullptr, mu, M);
    k_div<<<256, 256, 0, stream>>>(mu, cntA);
    k_dist<<<(M + 63) / 64, 256, 0, stream>>>(posz, mu, dist, rr, fb_assign, cntB, M);
    k_segsum<<<dim3(128, 8), 256, 0, stream>>>(posz, fb_assign, dist, u, M);
    k_div<<<256, 256, 0, stream>>>(u, cntB);
  }
}